// Round 2
// baseline (604.529 us; speedup 1.0000x reference)
//
#include <hip/hip_runtime.h>
#include <math.h>

#define DIMD 1024
#define CHUNKLEN 64
#define NTOK 16384   // B*S = 4*4096

#define TM 128
#define TN 128
#define BK 64

typedef __bf16 bf16x8 __attribute__((ext_vector_type(8)));
typedef float floatx4 __attribute__((ext_vector_type(4)));

__device__ __forceinline__ float bf2f(unsigned short u) {
  union { unsigned int i; float f; } v; v.i = ((unsigned int)u) << 16; return v.f;
}
__device__ __forceinline__ unsigned short f2bf(float f) {
  union { float f; unsigned int i; } v; v.f = f;
  unsigned int r = v.i + 0x7FFFu + ((v.i >> 16) & 1u);
  return (unsigned short)(r >> 16);
}

__device__ __forceinline__ void async16(const unsigned short* g, unsigned short* l) {
  __builtin_amdgcn_global_load_lds(
      (const __attribute__((address_space(1))) unsigned int*)g,
      (__attribute__((address_space(3))) unsigned int*)l, 16, 0, 0);
}

// fp32 -> bf16 convert, 4 elements/thread. n must be a multiple of 4.
__global__ __launch_bounds__(256) void cvt_kernel(
    const float* __restrict__ in, unsigned short* __restrict__ out, int n4)
{
  const int i = blockIdx.x * 256 + threadIdx.x;
  if (i < n4) {
    const float4 v = ((const float4*)in)[i];
    ushort4 o;
    o.x = f2bf(v.x); o.y = f2bf(v.y); o.z = f2bf(v.z); o.w = f2bf(v.w);
    ((ushort4*)out)[i] = o;
  }
}

// C = A[M,K] @ W[N,K]^T + bias[N]
// MODE 0: Cb (bf16) = acc + bias
// MODE 1: Cb (bf16) = tanh(acc + bias) * aux[col]          (phase fusion)
// MODE 2: Cf (f32)  = acc + bias + aux[row*N+col]          (residual, final)
template <int MODE>
__global__ __launch_bounds__(256) void gemm_bt_kernel(
    const unsigned short* __restrict__ A, const unsigned short* __restrict__ W,
    const float* __restrict__ bias, const float* __restrict__ aux,
    unsigned short* __restrict__ Cb, float* __restrict__ Cf,
    int M, int N, int K)
{
  __shared__ unsigned short lsA[TM * BK];
  __shared__ unsigned short lsB[TN * BK];

  const int tid  = threadIdx.x;
  const int lane = tid & 63;
  const int wid  = tid >> 6;
  const long bm  = (long)blockIdx.x * TM;
  const long bn  = (long)blockIdx.y * TN;
  const int wm   = (wid & 1) * 64;
  const int wn   = (wid >> 1) * 64;

  floatx4 acc[4][4];
#pragma unroll
  for (int i = 0; i < 4; ++i)
#pragma unroll
    for (int j = 0; j < 4; ++j)
      acc[i][j] = (floatx4)(0.0f);

  const int lrow = lane >> 3;        // 0..7
  const int lcol = (lane & 7) * 8;   // 0..56
  const int frm  = lane & 15;        // fragment m/n index
  const int frk  = (lane >> 4) * 8;  // fragment k base

  for (int kk = 0; kk < K; kk += BK) {
    __syncthreads();
#pragma unroll
    for (int j = 0; j < 4; ++j) {
      const int inst = wid * 4 + j;      // 0..15
      const int r = inst * 8 + lrow;     // 0..127
      async16(A + (bm + r) * (long)K + kk + lcol, &lsA[r * BK + lcol]);
      async16(W + (bn + r) * (long)K + kk + lcol, &lsB[r * BK + lcol]);
    }
    __syncthreads();
#pragma unroll
    for (int ks = 0; ks < BK; ks += 32) {
      bf16x8 af[4], bfr[4];
#pragma unroll
      for (int i = 0; i < 4; ++i)
        af[i]  = *(const bf16x8*)&lsA[(wm + i * 16 + frm) * BK + ks + frk];
#pragma unroll
      for (int i = 0; i < 4; ++i)
        bfr[i] = *(const bf16x8*)&lsB[(wn + i * 16 + frm) * BK + ks + frk];
#pragma unroll
      for (int i = 0; i < 4; ++i)
#pragma unroll
        for (int j = 0; j < 4; ++j)
          acc[i][j] = __builtin_amdgcn_mfma_f32_16x16x32_bf16(af[i], bfr[j], acc[i][j], 0, 0, 0);
    }
  }

  // epilogue: C/D layout col = lane&15, row = (lane>>4)*4 + reg
  const int cn = lane & 15;
  const int rq = (lane >> 4) * 4;
#pragma unroll
  for (int j = 0; j < 4; ++j) {
    const long col = bn + wn + j * 16 + cn;
    const float bv = bias[col];
    const float pv = (MODE == 1) ? aux[col] : 0.0f;
#pragma unroll
    for (int i = 0; i < 4; ++i) {
#pragma unroll
      for (int r = 0; r < 4; ++r) {
        const long row = bm + wm + i * 16 + rq + r;
        float v = acc[i][j][r] + bv;
        if (MODE == 0) {
          Cb[row * (long)N + col] = f2bf(v);
        } else if (MODE == 1) {
          Cb[row * (long)N + col] = f2bf(tanhf(v) * pv);
        } else {
          Cf[row * (long)N + col] = v + aux[row * (long)N + col];
        }
      }
    }
  }
}

// One block per (batch, chunk). 256 threads x 4 dims each.
// KP/QP already hold tanh(.)*phase. Cumsum of v*cos(kp)/v*sin(kp) over t,
// retrieved = (mr*cos(qp)+mi*sin(qp))/32, then row LayerNorm -> bf16 out.
__global__ __launch_bounds__(256) void scan_ln_kernel(
    const unsigned short* __restrict__ V,  const unsigned short* __restrict__ KP,
    const unsigned short* __restrict__ QP,
    const float* __restrict__ lng, const float* __restrict__ lnb,
    unsigned short* __restrict__ out)
{
  const int tid  = threadIdx.x;
  const int lane = tid & 63;
  const int wid  = tid >> 6;
  const long rowBase = (long)blockIdx.x * CHUNKLEN;
  const int d0 = tid * 4;

  float gg[4], bb[4];
#pragma unroll
  for (int j = 0; j < 4; ++j) {
    gg[j] = lng[d0 + j];
    bb[j] = lnb[d0 + j];
  }

  float mr[4] = {0.f, 0.f, 0.f, 0.f};
  float mi[4] = {0.f, 0.f, 0.f, 0.f};
  __shared__ float red[8];

  for (int t = 0; t < CHUNKLEN; ++t) {
    const long off = (rowBase + t) * DIMD + d0;
    const ushort4 v4 = *(const ushort4*)(V + off);
    const ushort4 k4 = *(const ushort4*)(KP + off);
    const ushort4 q4 = *(const ushort4*)(QP + off);
    const unsigned short va[4] = {v4.x, v4.y, v4.z, v4.w};
    const unsigned short ka[4] = {k4.x, k4.y, k4.z, k4.w};
    const unsigned short qa[4] = {q4.x, q4.y, q4.z, q4.w};

    float ret[4];
    float s = 0.f, s2 = 0.f;
#pragma unroll
    for (int j = 0; j < 4; ++j) {
      const float v  = bf2f(va[j]);
      const float kp = bf2f(ka[j]);
      const float qp = bf2f(qa[j]);
      float skp, ckp, sqp, cqp;
      __sincosf(kp, &skp, &ckp);
      __sincosf(qp, &sqp, &cqp);
      mr[j] += v * ckp;
      mi[j] += v * skp;
      const float r = (mr[j] * cqp + mi[j] * sqp) * 0.03125f; // /sqrt(1024)
      ret[j] = r;
      s  += r;
      s2 += r * r;
    }

    // block-wide mean/var over 1024 values
#pragma unroll
    for (int o = 32; o > 0; o >>= 1) {
      s  += __shfl_xor(s,  o, 64);
      s2 += __shfl_xor(s2, o, 64);
    }
    if (lane == 0) { red[wid] = s; red[4 + wid] = s2; }
    __syncthreads();
    const float S  = red[0] + red[1] + red[2] + red[3];
    const float S2 = red[4] + red[5] + red[6] + red[7];
    __syncthreads();

    const float mu  = S * (1.0f / DIMD);
    const float var = S2 * (1.0f / DIMD) - mu * mu;
    const float inv = rsqrtf(var + 1e-5f);

    ushort4 o4;
    o4.x = f2bf((ret[0] - mu) * inv * gg[0] + bb[0]);
    o4.y = f2bf((ret[1] - mu) * inv * gg[1] + bb[1]);
    o4.z = f2bf((ret[2] - mu) * inv * gg[2] + bb[2]);
    o4.w = f2bf((ret[3] - mu) * inv * gg[3] + bb[3]);
    *(ushort4*)(out + off) = o4;
  }
}

extern "C" void kernel_launch(void* const* d_in, const int* in_sizes, int n_in,
                              void* d_out, int out_size, void* d_ws, size_t ws_size,
                              hipStream_t stream)
{
  const float* x   = (const float*)d_in[0];
  const float* Wk  = (const float*)d_in[1];
  const float* bk  = (const float*)d_in[2];
  const float* Wv  = (const float*)d_in[3];
  const float* bv  = (const float*)d_in[4];
  const float* Wq  = (const float*)d_in[5];
  const float* bq  = (const float*)d_in[6];
  const float* Wkp = (const float*)d_in[7];
  const float* bkp = (const float*)d_in[8];
  const float* Wqp = (const float*)d_in[9];
  const float* bqp = (const float*)d_in[10];
  const float* ph  = (const float*)d_in[11];
  const float* lng = (const float*)d_in[12];
  const float* lnb = (const float*)d_in[13];
  const float* Wo  = (const float*)d_in[14];
  const float* bo  = (const float*)d_in[15];
  float* out = (float*)d_out;

  const long NB = (long)NTOK * DIMD;   // 16.7M elems
  const long DD = (long)DIMD * DIMD;   // 1M elems
  const size_t required = (size_t)(4 * NB + 6 * DD) * sizeof(unsigned short);
  if (ws_size < required) return;      // never fault the GPU; fail cleanly

  unsigned short* S0  = (unsigned short*)d_ws;   // xb, later Rln
  unsigned short* S1  = S0 + NB;                 // K -> Q -> V
  unsigned short* S2  = S1 + NB;                 // KP (phase)
  unsigned short* S3  = S2 + NB;                 // QP (phase)
  unsigned short* Wkb  = S3 + NB;
  unsigned short* Wvb  = Wkb + DD;
  unsigned short* Wqb  = Wvb + DD;
  unsigned short* Wkpb = Wqb + DD;
  unsigned short* Wqpb = Wkpb + DD;
  unsigned short* Wob  = Wqpb + DD;

  dim3 grid(NTOK / TM, DIMD / TN);
  dim3 blk(256);

  // fp32 -> bf16 conversions
  cvt_kernel<<<dim3((NB / 4 + 255) / 256), blk, 0, stream>>>(x, S0, (int)(NB / 4));
  const int w4 = (int)(DD / 4);
  dim3 wgrid((w4 + 255) / 256);
  cvt_kernel<<<wgrid, blk, 0, stream>>>(Wk,  Wkb,  w4);
  cvt_kernel<<<wgrid, blk, 0, stream>>>(Wv,  Wvb,  w4);
  cvt_kernel<<<wgrid, blk, 0, stream>>>(Wq,  Wqb,  w4);
  cvt_kernel<<<wgrid, blk, 0, stream>>>(Wkp, Wkpb, w4);
  cvt_kernel<<<wgrid, blk, 0, stream>>>(Wqp, Wqpb, w4);
  cvt_kernel<<<wgrid, blk, 0, stream>>>(Wo,  Wob,  w4);

  // K = x@Wk^T + bk ; KP = tanh(K@Wkp^T + bkp)*phase
  gemm_bt_kernel<0><<<grid, blk, 0, stream>>>(S0, Wkb,  bk,  nullptr, S1, nullptr, NTOK, DIMD, DIMD);
  gemm_bt_kernel<1><<<grid, blk, 0, stream>>>(S1, Wkpb, bkp, ph,      S2, nullptr, NTOK, DIMD, DIMD);
  // Q (reuses S1) ; QP
  gemm_bt_kernel<0><<<grid, blk, 0, stream>>>(S0, Wqb,  bq,  nullptr, S1, nullptr, NTOK, DIMD, DIMD);
  gemm_bt_kernel<1><<<grid, blk, 0, stream>>>(S1, Wqpb, bqp, ph,      S3, nullptr, NTOK, DIMD, DIMD);
  // V (reuses S1; xb dead after this)
  gemm_bt_kernel<0><<<grid, blk, 0, stream>>>(S0, Wvb,  bv,  nullptr, S1, nullptr, NTOK, DIMD, DIMD);

  // scan + layernorm -> Rln (reuses S0)
  scan_ln_kernel<<<dim3(NTOK / CHUNKLEN), blk, 0, stream>>>(S1, S2, S3, lng, lnb, S0);

  // out = Rln@Wo^T + bo + x   (fp32)
  gemm_bt_kernel<2><<<grid, blk, 0, stream>>>(S0, Wob, bo, x, nullptr, out, NTOK, DIMD, DIMD);
}

// Round 3
// 531.537 us; speedup vs baseline: 1.1373x; 1.1373x over previous
//
#include <hip/hip_runtime.h>
#include <math.h>

#define DIMD 1024
#define CHUNKLEN 64
#define NTOK 16384   // B*S = 4*4096

#define TM 128
#define TN 128
#define BK 64

typedef __bf16 bf16x8 __attribute__((ext_vector_type(8)));
typedef float floatx4 __attribute__((ext_vector_type(4)));

__device__ __forceinline__ float bf2f(unsigned short u) {
  union { unsigned int i; float f; } v; v.i = ((unsigned int)u) << 16; return v.f;
}
__device__ __forceinline__ unsigned short f2bf(float f) {
  union { float f; unsigned int i; } v; v.f = f;
  unsigned int r = v.i + 0x7FFFu + ((v.i >> 16) & 1u);
  return (unsigned short)(r >> 16);
}

__device__ __forceinline__ void async16(const unsigned short* g, unsigned short* l) {
  __builtin_amdgcn_global_load_lds(
      (const __attribute__((address_space(1))) unsigned int*)g,
      (__attribute__((address_space(3))) unsigned int*)l, 16, 0, 0);
}

// One dispatch converting x (16384 blocks) + 6 weights (1024 blocks each).
__global__ __launch_bounds__(256) void cvt_all_kernel(
    const float* __restrict__ x,
    const float* __restrict__ w0, const float* __restrict__ w1,
    const float* __restrict__ w2, const float* __restrict__ w3,
    const float* __restrict__ w4, const float* __restrict__ w5,
    unsigned short* __restrict__ dx,
    unsigned short* __restrict__ d0, unsigned short* __restrict__ d1,
    unsigned short* __restrict__ d2, unsigned short* __restrict__ d3,
    unsigned short* __restrict__ d4, unsigned short* __restrict__ d5)
{
  const int b = blockIdx.x;
  const float* src; unsigned short* dst; long i;
  if (b < 16384) {
    src = x; dst = dx; i = (long)b * 256 + threadIdx.x;
  } else {
    const int r = b - 16384;
    const int s = r >> 10;
    src = s == 0 ? w0 : s == 1 ? w1 : s == 2 ? w2 : s == 3 ? w3 : s == 4 ? w4 : w5;
    dst = s == 0 ? d0 : s == 1 ? d1 : s == 2 ? d2 : s == 3 ? d3 : s == 4 ? d4 : d5;
    i = (long)(r & 1023) * 256 + threadIdx.x;
  }
  const float4 v = ((const float4*)src)[i];
  ushort4 o;
  o.x = f2bf(v.x); o.y = f2bf(v.y); o.z = f2bf(v.z); o.w = f2bf(v.w);
  ((ushort4*)dst)[i] = o;
}

// C = A[M,1024] @ W[1024,1024]^T + bias, with XOR-swizzled LDS (conflict-free
// ds_read_b128: physical chunk p of row r holds logical chunk p^(r&7)).
// MODE 0: fused QKV. grid.y spans 3*1024/TN; per-block segment select of
//         W/bias/out. Out bf16.
// MODE 1: phase GEMM pair via blockIdx.z (z=0: A0/W0/b0->O0, z=1: A1/W1/b1->O1).
//         Out bf16 = tanh(acc+bias)*aux[col].
// MODE 2: final. Out f32 = acc + bias + resid[row*1024+col].
template <int MODE>
__global__ __launch_bounds__(256) void gemm_bt_kernel(
    const unsigned short* __restrict__ A0, const unsigned short* __restrict__ A1,
    const unsigned short* __restrict__ W0, const unsigned short* __restrict__ W1,
    const unsigned short* __restrict__ W2,
    const float* __restrict__ b0, const float* __restrict__ b1,
    const float* __restrict__ b2,
    const float* __restrict__ aux,
    unsigned short* __restrict__ O0, unsigned short* __restrict__ O1,
    unsigned short* __restrict__ O2,
    float* __restrict__ Of, const float* __restrict__ resid)
{
  __shared__ unsigned short lsA[TM * BK];
  __shared__ unsigned short lsB[TN * BK];

  const int tid  = threadIdx.x;
  const int lane = tid & 63;
  const int wid  = tid >> 6;
  const long bm  = (long)blockIdx.x * TM;
  const long bng = (long)blockIdx.y * TN;

  const unsigned short* A = A0;
  const unsigned short* W = W0;
  const float* bias = b0;
  unsigned short* Ob = O0;
  long bn = bng;
  if (MODE == 0) {
    const int seg = (int)(bng >> 10);
    bn = bng & 1023;
    W    = seg == 0 ? W0 : (seg == 1 ? W1 : W2);
    bias = seg == 0 ? b0 : (seg == 1 ? b1 : b2);
    Ob   = seg == 0 ? O0 : (seg == 1 ? O1 : O2);
  } else if (MODE == 1) {
    if (blockIdx.z) { A = A1; W = W1; bias = b1; Ob = O1; }
  }

  const int wm = (wid & 1) * 64;
  const int wn = (wid >> 1) * 64;

  floatx4 acc[4][4];
#pragma unroll
  for (int i = 0; i < 4; ++i)
#pragma unroll
    for (int j = 0; j < 4; ++j)
      acc[i][j] = (floatx4)(0.0f);

  // staging: lane L of instruction `inst` covers physical (row inst*8+(L>>3),
  // chunk L&7); it fetches logical chunk (L&7)^((L>>3)&7) from global.
  const int srow  = lane >> 3;                              // 0..7
  const int pcol  = (lane & 7) * 8;                         // physical chunk*8
  const int lcolL = (((lane & 7) ^ (srow & 7)) * 8);        // logical col (swizzled source)
  const int frm   = lane & 15;                              // fragment m/n
  const int cfrk  = lane >> 4;                              // frk/8 (0..3)

  for (int kk = 0; kk < DIMD; kk += BK) {
    __syncthreads();
#pragma unroll
    for (int j = 0; j < 4; ++j) {
      const int inst = wid * 4 + j;      // 0..15
      const int r = inst * 8 + srow;     // 0..127
      async16(A + (bm + r) * (long)DIMD + kk + lcolL, &lsA[r * BK + pcol]);
      async16(W + (bn + r) * (long)DIMD + kk + lcolL, &lsB[r * BK + pcol]);
    }
    __syncthreads();
#pragma unroll
    for (int ks = 0; ks < BK; ks += 32) {
      const int cb  = (ks >> 3) + cfrk;                 // logical chunk 0..7
      const int swz = ((cb ^ (frm & 7)) << 3);          // physical col offset
      bf16x8 af[4], bfr[4];
#pragma unroll
      for (int i = 0; i < 4; ++i)
        af[i]  = *(const bf16x8*)&lsA[(wm + i * 16 + frm) * BK + swz];
#pragma unroll
      for (int i = 0; i < 4; ++i)
        bfr[i] = *(const bf16x8*)&lsB[(wn + i * 16 + frm) * BK + swz];
#pragma unroll
      for (int i = 0; i < 4; ++i)
#pragma unroll
        for (int j = 0; j < 4; ++j)
          acc[i][j] = __builtin_amdgcn_mfma_f32_16x16x32_bf16(af[i], bfr[j], acc[i][j], 0, 0, 0);
    }
  }

  // epilogue: C/D layout col = lane&15, row = (lane>>4)*4 + reg
  const int cn = lane & 15;
  const int rq = (lane >> 4) * 4;
#pragma unroll
  for (int j = 0; j < 4; ++j) {
    const long col = bn + wn + j * 16 + cn;
    const float bv = bias[col];
    const float pv = (MODE == 1) ? aux[col] : 0.0f;
#pragma unroll
    for (int i = 0; i < 4; ++i) {
#pragma unroll
      for (int r = 0; r < 4; ++r) {
        const long row = bm + wm + i * 16 + rq + r;
        const float v = acc[i][j][r] + bv;
        if (MODE == 0) {
          Ob[row * (long)DIMD + col] = f2bf(v);
        } else if (MODE == 1) {
          Ob[row * (long)DIMD + col] = f2bf(tanhf(v) * pv);
        } else {
          Of[row * (long)DIMD + col] = v + resid[row * (long)DIMD + col];
        }
      }
    }
  }
}

// One block per (batch, chunk). 256 threads x 4 dims each.
// KP/QP already hold tanh(.)*phase. Cumsum of v*cos(kp)/v*sin(kp) over t,
// retrieved = (mr*cos(qp)+mi*sin(qp))/32, then row LayerNorm -> bf16 out.
__global__ __launch_bounds__(256) void scan_ln_kernel(
    const unsigned short* __restrict__ V,  const unsigned short* __restrict__ KP,
    const unsigned short* __restrict__ QP,
    const float* __restrict__ lng, const float* __restrict__ lnb,
    unsigned short* __restrict__ out)
{
  const int tid  = threadIdx.x;
  const int lane = tid & 63;
  const int wid  = tid >> 6;
  const long rowBase = (long)blockIdx.x * CHUNKLEN;
  const int d0 = tid * 4;

  float gg[4], bb[4];
#pragma unroll
  for (int j = 0; j < 4; ++j) {
    gg[j] = lng[d0 + j];
    bb[j] = lnb[d0 + j];
  }

  float mr[4] = {0.f, 0.f, 0.f, 0.f};
  float mi[4] = {0.f, 0.f, 0.f, 0.f};
  __shared__ float red[8];

  for (int t = 0; t < CHUNKLEN; ++t) {
    const long off = (rowBase + t) * DIMD + d0;
    const ushort4 v4 = *(const ushort4*)(V + off);
    const ushort4 k4 = *(const ushort4*)(KP + off);
    const ushort4 q4 = *(const ushort4*)(QP + off);
    const unsigned short va[4] = {v4.x, v4.y, v4.z, v4.w};
    const unsigned short ka[4] = {k4.x, k4.y, k4.z, k4.w};
    const unsigned short qa[4] = {q4.x, q4.y, q4.z, q4.w};

    float ret[4];
    float s = 0.f, s2 = 0.f;
#pragma unroll
    for (int j = 0; j < 4; ++j) {
      const float v  = bf2f(va[j]);
      const float kp = bf2f(ka[j]);
      const float qp = bf2f(qa[j]);
      float skp, ckp, sqp, cqp;
      __sincosf(kp, &skp, &ckp);
      __sincosf(qp, &sqp, &cqp);
      mr[j] += v * ckp;
      mi[j] += v * skp;
      const float r = (mr[j] * cqp + mi[j] * sqp) * 0.03125f; // /sqrt(1024)
      ret[j] = r;
      s  += r;
      s2 += r * r;
    }

#pragma unroll
    for (int o = 32; o > 0; o >>= 1) {
      s  += __shfl_xor(s,  o, 64);
      s2 += __shfl_xor(s2, o, 64);
    }
    if (lane == 0) { red[wid] = s; red[4 + wid] = s2; }
    __syncthreads();
    const float S  = red[0] + red[1] + red[2] + red[3];
    const float S2 = red[4] + red[5] + red[6] + red[7];
    __syncthreads();

    const float mu  = S * (1.0f / DIMD);
    const float var = S2 * (1.0f / DIMD) - mu * mu;
    const float inv = rsqrtf(var + 1e-5f);

    ushort4 o4;
    o4.x = f2bf((ret[0] - mu) * inv * gg[0] + bb[0]);
    o4.y = f2bf((ret[1] - mu) * inv * gg[1] + bb[1]);
    o4.z = f2bf((ret[2] - mu) * inv * gg[2] + bb[2]);
    o4.w = f2bf((ret[3] - mu) * inv * gg[3] + bb[3]);
    *(ushort4*)(out + off) = o4;
  }
}

extern "C" void kernel_launch(void* const* d_in, const int* in_sizes, int n_in,
                              void* d_out, int out_size, void* d_ws, size_t ws_size,
                              hipStream_t stream)
{
  const float* x   = (const float*)d_in[0];
  const float* Wk  = (const float*)d_in[1];
  const float* bk  = (const float*)d_in[2];
  const float* Wv  = (const float*)d_in[3];
  const float* bv  = (const float*)d_in[4];
  const float* Wq  = (const float*)d_in[5];
  const float* bq  = (const float*)d_in[6];
  const float* Wkp = (const float*)d_in[7];
  const float* bkp = (const float*)d_in[8];
  const float* Wqp = (const float*)d_in[9];
  const float* bqp = (const float*)d_in[10];
  const float* ph  = (const float*)d_in[11];
  const float* lng = (const float*)d_in[12];
  const float* lnb = (const float*)d_in[13];
  const float* Wo  = (const float*)d_in[14];
  const float* bo  = (const float*)d_in[15];
  float* out = (float*)d_out;

  const long NB = (long)NTOK * DIMD;
  const long DD = (long)DIMD * DIMD;
  const size_t need_fused = (size_t)(6 * NB + 6 * DD) * sizeof(unsigned short);
  const size_t need_seq   = (size_t)(4 * NB + 6 * DD) * sizeof(unsigned short);

  dim3 blk(256);
  const dim3 cvt_grid(16384 + 6 * 1024);

  if (ws_size >= need_fused) {
    unsigned short* S0  = (unsigned short*)d_ws;   // xb, later Rln
    unsigned short* SK  = S0  + NB;
    unsigned short* SV  = SK  + NB;
    unsigned short* SQ  = SV  + NB;
    unsigned short* SKP = SQ  + NB;
    unsigned short* SQP = SKP + NB;
    unsigned short* Wkb  = SQP + NB;
    unsigned short* Wvb  = Wkb + DD;
    unsigned short* Wqb  = Wvb + DD;
    unsigned short* Wkpb = Wqb + DD;
    unsigned short* Wqpb = Wkpb + DD;
    unsigned short* Wob  = Wqpb + DD;

    cvt_all_kernel<<<cvt_grid, blk, 0, stream>>>(
        x, Wk, Wv, Wq, Wkp, Wqp, Wo, S0, Wkb, Wvb, Wqb, Wkpb, Wqpb, Wob);

    // fused QKV: N = 3072
    gemm_bt_kernel<0><<<dim3(NTOK / TM, 3 * DIMD / TN), blk, 0, stream>>>(
        S0, nullptr, Wkb, Wvb, Wqb, bk, bv, bq, nullptr, SK, SV, SQ, nullptr, nullptr);
    // fused phase pair: z=0 -> KP from K, z=1 -> QP from Q
    gemm_bt_kernel<1><<<dim3(NTOK / TM, DIMD / TN, 2), blk, 0, stream>>>(
        SK, SQ, Wkpb, Wqpb, nullptr, bkp, bqp, nullptr, ph, SKP, SQP, nullptr, nullptr, nullptr);

    scan_ln_kernel<<<dim3(NTOK / CHUNKLEN), blk, 0, stream>>>(SV, SKP, SQP, lng, lnb, S0);

    gemm_bt_kernel<2><<<dim3(NTOK / TM, DIMD / TN), blk, 0, stream>>>(
        S0, nullptr, Wob, nullptr, nullptr, bo, nullptr, nullptr, nullptr,
        nullptr, nullptr, nullptr, out, x);
  } else if (ws_size >= need_seq) {
    unsigned short* S0  = (unsigned short*)d_ws;   // xb, later Rln
    unsigned short* S1  = S0 + NB;                 // K -> Q -> V
    unsigned short* S2  = S1 + NB;                 // KP
    unsigned short* S3  = S2 + NB;                 // QP
    unsigned short* Wkb  = S3 + NB;
    unsigned short* Wvb  = Wkb + DD;
    unsigned short* Wqb  = Wvb + DD;
    unsigned short* Wkpb = Wqb + DD;
    unsigned short* Wqpb = Wkpb + DD;
    unsigned short* Wob  = Wqpb + DD;

    cvt_all_kernel<<<cvt_grid, blk, 0, stream>>>(
        x, Wk, Wv, Wq, Wkp, Wqp, Wo, S0, Wkb, Wvb, Wqb, Wkpb, Wqpb, Wob);

    dim3 g1(NTOK / TM, DIMD / TN);
    // K -> KP
    gemm_bt_kernel<0><<<g1, blk, 0, stream>>>(
        S0, nullptr, Wkb, nullptr, nullptr, bk, nullptr, nullptr, nullptr,
        S1, nullptr, nullptr, nullptr, nullptr);
    gemm_bt_kernel<1><<<g1, blk, 0, stream>>>(
        S1, nullptr, Wkpb, nullptr, nullptr, bkp, nullptr, nullptr, ph,
        S2, nullptr, nullptr, nullptr, nullptr);
    // Q -> QP
    gemm_bt_kernel<0><<<g1, blk, 0, stream>>>(
        S0, nullptr, Wqb, nullptr, nullptr, bq, nullptr, nullptr, nullptr,
        S1, nullptr, nullptr, nullptr, nullptr);
    gemm_bt_kernel<1><<<g1, blk, 0, stream>>>(
        S1, nullptr, Wqpb, nullptr, nullptr, bqp, nullptr, nullptr, ph,
        S3, nullptr, nullptr, nullptr, nullptr);
    // V
    gemm_bt_kernel<0><<<g1, blk, 0, stream>>>(
        S0, nullptr, Wvb, nullptr, nullptr, bv, nullptr, nullptr, nullptr,
        S1, nullptr, nullptr, nullptr, nullptr);

    scan_ln_kernel<<<dim3(NTOK / CHUNKLEN), blk, 0, stream>>>(S1, S2, S3, lng, lnb, S0);

    gemm_bt_kernel<2><<<g1, blk, 0, stream>>>(
        S0, nullptr, Wob, nullptr, nullptr, bo, nullptr, nullptr, nullptr,
        nullptr, nullptr, nullptr, out, x);
  }
}

// Round 4
// 509.022 us; speedup vs baseline: 1.1876x; 1.0442x over previous
//
#include <hip/hip_runtime.h>
#include <math.h>

#define DIMD 1024
#define CHUNKLEN 64
#define NTOK 16384   // B*S = 4*4096

#define TM 128
#define TN 128
#define BK 64

typedef __bf16 bf16x8 __attribute__((ext_vector_type(8)));
typedef float floatx4 __attribute__((ext_vector_type(4)));

__device__ __forceinline__ float bf2f(unsigned short u) {
  union { unsigned int i; float f; } v; v.i = ((unsigned int)u) << 16; return v.f;
}
__device__ __forceinline__ unsigned short f2bf(float f) {
  union { float f; unsigned int i; } v; v.f = f;
  unsigned int r = v.i + 0x7FFFu + ((v.i >> 16) & 1u);
  return (unsigned short)(r >> 16);
}

__device__ __forceinline__ void async16(const unsigned short* g, unsigned short* l) {
  __builtin_amdgcn_global_load_lds(
      (const __attribute__((address_space(1))) unsigned int*)g,
      (__attribute__((address_space(3))) unsigned int*)l, 16, 0, 0);
}

// One dispatch converting x (16384 blocks) + 6 weights (1024 blocks each).
__global__ __launch_bounds__(256) void cvt_all_kernel(
    const float* __restrict__ x,
    const float* __restrict__ w0, const float* __restrict__ w1,
    const float* __restrict__ w2, const float* __restrict__ w3,
    const float* __restrict__ w4, const float* __restrict__ w5,
    unsigned short* __restrict__ dx,
    unsigned short* __restrict__ d0, unsigned short* __restrict__ d1,
    unsigned short* __restrict__ d2, unsigned short* __restrict__ d3,
    unsigned short* __restrict__ d4, unsigned short* __restrict__ d5)
{
  const int b = blockIdx.x;
  const float* src; unsigned short* dst; long i;
  if (b < 16384) {
    src = x; dst = dx; i = (long)b * 256 + threadIdx.x;
  } else {
    const int r = b - 16384;
    const int s = r >> 10;
    src = s == 0 ? w0 : s == 1 ? w1 : s == 2 ? w2 : s == 3 ? w3 : s == 4 ? w4 : w5;
    dst = s == 0 ? d0 : s == 1 ? d1 : s == 2 ? d2 : s == 3 ? d3 : s == 4 ? d4 : d5;
    i = (long)(r & 1023) * 256 + threadIdx.x;
  }
  const float4 v = ((const float4*)src)[i];
  ushort4 o;
  o.x = f2bf(v.x); o.y = f2bf(v.y); o.z = f2bf(v.z); o.w = f2bf(v.w);
  ((ushort4*)dst)[i] = o;
}

// C = A[M,1024] @ W[1024,1024]^T + bias, XOR-swizzled LDS (0 bank conflicts).
// Grid is (N-blocks, M-blocks[, z]) — N fastest for L2 W-residency per XCD.
// MODE 0: fused QKV. blockIdx.x spans 3*1024/TN; per-block segment select.
// MODE 1: phase GEMM pair via blockIdx.z. Out bf16 = tanh(acc+bias)*aux[col].
// MODE 2: final. Out f32 = acc + bias + resid[row*1024+col].
template <int MODE>
__global__ __launch_bounds__(256) void gemm_bt_kernel(
    const unsigned short* __restrict__ A0, const unsigned short* __restrict__ A1,
    const unsigned short* __restrict__ W0, const unsigned short* __restrict__ W1,
    const unsigned short* __restrict__ W2,
    const float* __restrict__ b0, const float* __restrict__ b1,
    const float* __restrict__ b2,
    const float* __restrict__ aux,
    unsigned short* __restrict__ O0, unsigned short* __restrict__ O1,
    unsigned short* __restrict__ O2,
    float* __restrict__ Of, const float* __restrict__ resid)
{
  __shared__ unsigned short lsA[TM * BK];
  __shared__ unsigned short lsB[TN * BK];

  const int tid  = threadIdx.x;
  const int lane = tid & 63;
  const int wid  = tid >> 6;
  const long bm  = (long)blockIdx.y * TM;      // M from y (slow)
  const long bng = (long)blockIdx.x * TN;      // N from x (fast) -> L2 locality

  const unsigned short* A = A0;
  const unsigned short* W = W0;
  const float* bias = b0;
  unsigned short* Ob = O0;
  long bn = bng;
  if (MODE == 0) {
    const int seg = (int)(bng >> 10);
    bn = bng & 1023;
    W    = seg == 0 ? W0 : (seg == 1 ? W1 : W2);
    bias = seg == 0 ? b0 : (seg == 1 ? b1 : b2);
    Ob   = seg == 0 ? O0 : (seg == 1 ? O1 : O2);
  } else if (MODE == 1) {
    if (blockIdx.z) { A = A1; W = W1; bias = b1; Ob = O1; }
  }

  const int wm = (wid & 1) * 64;
  const int wn = (wid >> 1) * 64;

  floatx4 acc[4][4];
#pragma unroll
  for (int i = 0; i < 4; ++i)
#pragma unroll
    for (int j = 0; j < 4; ++j)
      acc[i][j] = (floatx4)(0.0f);

  const int srow  = lane >> 3;                              // 0..7
  const int pcol  = (lane & 7) * 8;                         // physical chunk*8
  const int lcolL = (((lane & 7) ^ (srow & 7)) * 8);        // swizzled source col
  const int frm   = lane & 15;
  const int cfrk  = lane >> 4;

  for (int kk = 0; kk < DIMD; kk += BK) {
    __syncthreads();
#pragma unroll
    for (int j = 0; j < 4; ++j) {
      const int inst = wid * 4 + j;
      const int r = inst * 8 + srow;
      async16(A + (bm + r) * (long)DIMD + kk + lcolL, &lsA[r * BK + pcol]);
      async16(W + (bn + r) * (long)DIMD + kk + lcolL, &lsB[r * BK + pcol]);
    }
    __syncthreads();
#pragma unroll
    for (int ks = 0; ks < BK; ks += 32) {
      const int cb  = (ks >> 3) + cfrk;
      const int swz = ((cb ^ (frm & 7)) << 3);
      bf16x8 af[4], bfr[4];
#pragma unroll
      for (int i = 0; i < 4; ++i)
        af[i]  = *(const bf16x8*)&lsA[(wm + i * 16 + frm) * BK + swz];
#pragma unroll
      for (int i = 0; i < 4; ++i)
        bfr[i] = *(const bf16x8*)&lsB[(wn + i * 16 + frm) * BK + swz];
#pragma unroll
      for (int i = 0; i < 4; ++i)
#pragma unroll
        for (int j = 0; j < 4; ++j)
          acc[i][j] = __builtin_amdgcn_mfma_f32_16x16x32_bf16(af[i], bfr[j], acc[i][j], 0, 0, 0);
    }
  }

  const int cn = lane & 15;
  const int rq = (lane >> 4) * 4;
#pragma unroll
  for (int j = 0; j < 4; ++j) {
    const long col = bn + wn + j * 16 + cn;
    const float bv = bias[col];
    const float pv = (MODE == 1) ? aux[col] : 0.0f;
#pragma unroll
    for (int i = 0; i < 4; ++i) {
#pragma unroll
      for (int r = 0; r < 4; ++r) {
        const long row = bm + wm + i * 16 + rq + r;
        const float v = acc[i][j][r] + bv;
        if (MODE == 0) {
          Ob[row * (long)DIMD + col] = f2bf(v);
        } else if (MODE == 1) {
          Ob[row * (long)DIMD + col] = f2bf(tanhf(v) * pv);
        } else {
          Of[row * (long)DIMD + col] = v + resid[row * (long)DIMD + col];
        }
      }
    }
  }
}

typedef unsigned short ushort8v __attribute__((ext_vector_type(8)));

// One block per chunk, 256 threads x 4 dims. Two halves of 32 t-steps:
// phase 1 (barrier-free): per-thread scan, retrieved -> LDS (bf16).
// phase 2: per-row LN via wave shuffle reduce, coalesced 16B stores.
__global__ __launch_bounds__(256) void scan_ln_kernel(
    const unsigned short* __restrict__ V,  const unsigned short* __restrict__ KP,
    const unsigned short* __restrict__ QP,
    const float* __restrict__ lng, const float* __restrict__ lnb,
    unsigned short* __restrict__ out)
{
  __shared__ unsigned short ret_s[32][DIMD];   // 64 KB

  const int tid  = threadIdx.x;
  const int lane = tid & 63;
  const int wid  = tid >> 6;
  const long rowBase = (long)blockIdx.x * CHUNKLEN;
  const int d0 = tid * 4;

  // phase-2 column ownership: chunk lane (cols c0..c0+7) and chunk 64+lane
  const int c0 = lane * 8;
  const int c1 = 512 + lane * 8;
  float g0[8], be0[8], g1[8], be1[8];
#pragma unroll
  for (int j = 0; j < 8; ++j) {
    g0[j] = lng[c0 + j]; be0[j] = lnb[c0 + j];
    g1[j] = lng[c1 + j]; be1[j] = lnb[c1 + j];
  }

  float mr[4] = {0.f, 0.f, 0.f, 0.f};
  float mi[4] = {0.f, 0.f, 0.f, 0.f};

  for (int h = 0; h < 2; ++h) {
    // ---- phase 1: scan 32 steps, no barriers ----
    for (int tl = 0; tl < 32; ++tl) {
      const int t = h * 32 + tl;
      const long off = (rowBase + t) * DIMD + d0;
      const ushort4 v4 = *(const ushort4*)(V + off);
      const ushort4 k4 = *(const ushort4*)(KP + off);
      const ushort4 q4 = *(const ushort4*)(QP + off);
      const unsigned short va[4] = {v4.x, v4.y, v4.z, v4.w};
      const unsigned short ka[4] = {k4.x, k4.y, k4.z, k4.w};
      const unsigned short qa[4] = {q4.x, q4.y, q4.z, q4.w};
      ushort4 o4;
      unsigned short rv[4];
#pragma unroll
      for (int j = 0; j < 4; ++j) {
        const float v  = bf2f(va[j]);
        const float kp = bf2f(ka[j]);
        const float qp = bf2f(qa[j]);
        float skp, ckp, sqp, cqp;
        __sincosf(kp, &skp, &ckp);
        __sincosf(qp, &sqp, &cqp);
        mr[j] += v * ckp;
        mi[j] += v * skp;
        rv[j] = f2bf((mr[j] * cqp + mi[j] * sqp) * 0.03125f);
      }
      o4.x = rv[0]; o4.y = rv[1]; o4.z = rv[2]; o4.w = rv[3];
      *(ushort4*)&ret_s[tl][d0] = o4;
    }
    __syncthreads();

    // ---- phase 2: 8 rows per wave, shuffle-reduce LN ----
#pragma unroll 1
    for (int rr = 0; rr < 8; ++rr) {
      const int tl = wid * 8 + rr;
      const ushort8v a0 = *(const ushort8v*)&ret_s[tl][c0];
      const ushort8v a1 = *(const ushort8v*)&ret_s[tl][c1];
      float f0[8], f1[8];
      float s = 0.f, s2 = 0.f;
#pragma unroll
      for (int j = 0; j < 8; ++j) {
        f0[j] = bf2f(a0[j]); f1[j] = bf2f(a1[j]);
        s += f0[j] + f1[j];
        s2 += f0[j] * f0[j] + f1[j] * f1[j];
      }
#pragma unroll
      for (int o = 32; o > 0; o >>= 1) {
        s  += __shfl_xor(s,  o, 64);
        s2 += __shfl_xor(s2, o, 64);
      }
      const float mu  = s * (1.0f / DIMD);
      const float var = s2 * (1.0f / DIMD) - mu * mu;
      const float inv = rsqrtf(var + 1e-5f);
      ushort8v o0, o1;
#pragma unroll
      for (int j = 0; j < 8; ++j) {
        o0[j] = f2bf((f0[j] - mu) * inv * g0[j] + be0[j]);
        o1[j] = f2bf((f1[j] - mu) * inv * g1[j] + be1[j]);
      }
      const long gro = (rowBase + h * 32 + tl) * DIMD;
      *(ushort8v*)(out + gro + c0) = o0;
      *(ushort8v*)(out + gro + c1) = o1;
    }
    __syncthreads();   // protect ret_s before next half overwrites
  }
}

extern "C" void kernel_launch(void* const* d_in, const int* in_sizes, int n_in,
                              void* d_out, int out_size, void* d_ws, size_t ws_size,
                              hipStream_t stream)
{
  const float* x   = (const float*)d_in[0];
  const float* Wk  = (const float*)d_in[1];
  const float* bk  = (const float*)d_in[2];
  const float* Wv  = (const float*)d_in[3];
  const float* bv  = (const float*)d_in[4];
  const float* Wq  = (const float*)d_in[5];
  const float* bq  = (const float*)d_in[6];
  const float* Wkp = (const float*)d_in[7];
  const float* bkp = (const float*)d_in[8];
  const float* Wqp = (const float*)d_in[9];
  const float* bqp = (const float*)d_in[10];
  const float* ph  = (const float*)d_in[11];
  const float* lng = (const float*)d_in[12];
  const float* lnb = (const float*)d_in[13];
  const float* Wo  = (const float*)d_in[14];
  const float* bo  = (const float*)d_in[15];
  float* out = (float*)d_out;

  const long NB = (long)NTOK * DIMD;
  const long DD = (long)DIMD * DIMD;
  const size_t need_fused = (size_t)(6 * NB + 6 * DD) * sizeof(unsigned short);
  const size_t need_seq   = (size_t)(4 * NB + 6 * DD) * sizeof(unsigned short);

  dim3 blk(256);
  const dim3 cvt_grid(16384 + 6 * 1024);

  if (ws_size >= need_fused) {
    unsigned short* S0  = (unsigned short*)d_ws;   // xb, later Rln
    unsigned short* SK  = S0  + NB;
    unsigned short* SV  = SK  + NB;
    unsigned short* SQ  = SV  + NB;
    unsigned short* SKP = SQ  + NB;
    unsigned short* SQP = SKP + NB;
    unsigned short* Wkb  = SQP + NB;
    unsigned short* Wvb  = Wkb + DD;
    unsigned short* Wqb  = Wvb + DD;
    unsigned short* Wkpb = Wqb + DD;
    unsigned short* Wqpb = Wkpb + DD;
    unsigned short* Wob  = Wqpb + DD;

    cvt_all_kernel<<<cvt_grid, blk, 0, stream>>>(
        x, Wk, Wv, Wq, Wkp, Wqp, Wo, S0, Wkb, Wvb, Wqb, Wkpb, Wqpb, Wob);

    // fused QKV: N = 3072, N-fastest grid
    gemm_bt_kernel<0><<<dim3(3 * DIMD / TN, NTOK / TM), blk, 0, stream>>>(
        S0, nullptr, Wkb, Wvb, Wqb, bk, bv, bq, nullptr, SK, SV, SQ, nullptr, nullptr);
    // fused phase pair: z=0 -> KP from K, z=1 -> QP from Q
    gemm_bt_kernel<1><<<dim3(DIMD / TN, NTOK / TM, 2), blk, 0, stream>>>(
        SK, SQ, Wkpb, Wqpb, nullptr, bkp, bqp, nullptr, ph, SKP, SQP, nullptr, nullptr, nullptr);

    scan_ln_kernel<<<dim3(NTOK / CHUNKLEN), blk, 0, stream>>>(SV, SKP, SQP, lng, lnb, S0);

    gemm_bt_kernel<2><<<dim3(DIMD / TN, NTOK / TM), blk, 0, stream>>>(
        S0, nullptr, Wob, nullptr, nullptr, bo, nullptr, nullptr, nullptr,
        nullptr, nullptr, nullptr, out, x);
  } else if (ws_size >= need_seq) {
    unsigned short* S0  = (unsigned short*)d_ws;
    unsigned short* S1  = S0 + NB;
    unsigned short* S2  = S1 + NB;
    unsigned short* S3  = S2 + NB;
    unsigned short* Wkb  = S3 + NB;
    unsigned short* Wvb  = Wkb + DD;
    unsigned short* Wqb  = Wvb + DD;
    unsigned short* Wkpb = Wqb + DD;
    unsigned short* Wqpb = Wkpb + DD;
    unsigned short* Wob  = Wqpb + DD;

    cvt_all_kernel<<<cvt_grid, blk, 0, stream>>>(
        x, Wk, Wv, Wq, Wkp, Wqp, Wo, S0, Wkb, Wvb, Wqb, Wkpb, Wqpb, Wob);

    dim3 g1(DIMD / TN, NTOK / TM);
    gemm_bt_kernel<0><<<g1, blk, 0, stream>>>(
        S0, nullptr, Wkb, nullptr, nullptr, bk, nullptr, nullptr, nullptr,
        S1, nullptr, nullptr, nullptr, nullptr);
    gemm_bt_kernel<1><<<g1, blk, 0, stream>>>(
        S1, nullptr, Wkpb, nullptr, nullptr, bkp, nullptr, nullptr, ph,
        S2, nullptr, nullptr, nullptr, nullptr);
    gemm_bt_kernel<0><<<g1, blk, 0, stream>>>(
        S0, nullptr, Wqb, nullptr, nullptr, bq, nullptr, nullptr, nullptr,
        S1, nullptr, nullptr, nullptr, nullptr);
    gemm_bt_kernel<1><<<g1, blk, 0, stream>>>(
        S1, nullptr, Wqpb, nullptr, nullptr, bqp, nullptr, nullptr, ph,
        S3, nullptr, nullptr, nullptr, nullptr);
    gemm_bt_kernel<0><<<g1, blk, 0, stream>>>(
        S0, nullptr, Wvb, nullptr, nullptr, bv, nullptr, nullptr, nullptr,
        S1, nullptr, nullptr, nullptr, nullptr);

    scan_ln_kernel<<<dim3(NTOK / CHUNKLEN), blk, 0, stream>>>(S1, S2, S3, lng, lnb, S0);

    gemm_bt_kernel<2><<<g1, blk, 0, stream>>>(
        S0, nullptr, Wob, nullptr, nullptr, bo, nullptr, nullptr, nullptr,
        nullptr, nullptr, nullptr, out, x);
  }
}

// Round 5
// 450.931 us; speedup vs baseline: 1.3406x; 1.1288x over previous
//
#include <hip/hip_runtime.h>
#include <math.h>

#define DIMD 1024
#define CHUNKLEN 64
#define NTOK 16384   // B*S = 4*4096

#define TM 128
#define TN 128
#define BK 64

typedef __bf16 bf16x8 __attribute__((ext_vector_type(8)));
typedef float floatx4 __attribute__((ext_vector_type(4)));
typedef unsigned short ushort8v __attribute__((ext_vector_type(8)));

__device__ __forceinline__ float bf2f(unsigned short u) {
  union { unsigned int i; float f; } v; v.i = ((unsigned int)u) << 16; return v.f;
}
__device__ __forceinline__ unsigned short f2bf(float f) {
  union { float f; unsigned int i; } v; v.f = f;
  unsigned int r = v.i + 0x7FFFu + ((v.i >> 16) & 1u);
  return (unsigned short)(r >> 16);
}

__device__ __forceinline__ void async16(const unsigned short* g, unsigned short* l) {
  __builtin_amdgcn_global_load_lds(
      (const __attribute__((address_space(1))) unsigned int*)g,
      (__attribute__((address_space(3))) unsigned int*)l, 16, 0, 0);
}

// Convert x (16384 blocks) + 4 weights (1024 blocks each) fp32 -> bf16.
__global__ __launch_bounds__(256) void cvt_all_kernel(
    const float* __restrict__ x,
    const float* __restrict__ w0, const float* __restrict__ w1,
    const float* __restrict__ w2, const float* __restrict__ w3,
    unsigned short* __restrict__ dx,
    unsigned short* __restrict__ d0, unsigned short* __restrict__ d1,
    unsigned short* __restrict__ d2, unsigned short* __restrict__ d3)
{
  const int b = blockIdx.x;
  const float* src; unsigned short* dst; long i;
  if (b < 16384) {
    src = x; dst = dx; i = (long)b * 256 + threadIdx.x;
  } else {
    const int r = b - 16384;
    const int s = r >> 10;
    src = s == 0 ? w0 : s == 1 ? w1 : s == 2 ? w2 : w3;
    dst = s == 0 ? d0 : s == 1 ? d1 : s == 2 ? d2 : d3;
    i = (long)(r & 1023) * 256 + threadIdx.x;
  }
  const float4 v = ((const float4*)src)[i];
  ushort4 o;
  o.x = f2bf(v.x); o.y = f2bf(v.y); o.z = f2bf(v.z); o.w = f2bf(v.w);
  ((ushort4*)dst)[i] = o;
}

// dst[k*1024+e] = bf16(src[e*1024+k]) for two matrices (z selects).
__global__ __launch_bounds__(256) void transpose_cvt_kernel(
    const float* __restrict__ s0, const float* __restrict__ s1,
    unsigned short* __restrict__ q0, unsigned short* __restrict__ q1)
{
  __shared__ unsigned short tile[64][66];
  const float* src = blockIdx.z ? s1 : s0;
  unsigned short* dst = blockIdx.z ? q1 : q0;
  const int e0 = blockIdx.y * 64;
  const int k0 = blockIdx.x * 64;
  const int t  = threadIdx.x;
  const int tr = t >> 4;        // 0..15
  const int tc = t & 15;        // 0..15
#pragma unroll
  for (int p = 0; p < 4; ++p) {
    const int el = p * 16 + tr;
    const float4 v = *(const float4*)&src[(long)(e0 + el) * DIMD + k0 + tc * 4];
    tile[el][tc * 4 + 0] = f2bf(v.x);
    tile[el][tc * 4 + 1] = f2bf(v.y);
    tile[el][tc * 4 + 2] = f2bf(v.z);
    tile[el][tc * 4 + 3] = f2bf(v.w);
  }
  __syncthreads();
#pragma unroll
  for (int p = 0; p < 4; ++p) {
    const int kl = p * 16 + tr;
    ushort4 o;
    o.x = tile[tc * 4 + 0][kl];
    o.y = tile[tc * 4 + 1][kl];
    o.z = tile[tc * 4 + 2][kl];
    o.w = tile[tc * 4 + 3][kl];
    *(ushort4*)&dst[(long)(k0 + kl) * DIMD + e0 + tc * 4] = o;
  }
}

// bkq[n] = sum_e Wkp[n,e]*bk[e] + bkp[n]; same for q-pair. 512 blocks x 4 waves.
__global__ __launch_bounds__(256) void bias_comb_kernel(
    const float* __restrict__ Wkp, const float* __restrict__ bk,
    const float* __restrict__ bkp,
    const float* __restrict__ Wqp, const float* __restrict__ bq,
    const float* __restrict__ bqp,
    float* __restrict__ bkq, float* __restrict__ bqq)
{
  const int b = blockIdx.x;
  const int which = b >> 8;
  const int lane = threadIdx.x & 63;
  const int wid  = threadIdx.x >> 6;
  const int n = (b & 255) * 4 + wid;
  const float* W    = which ? Wqp : Wkp;
  const float* bvec = which ? bq  : bk;
  const float* badd = which ? bqp : bkp;
  float*       outp = which ? bqq : bkq;
  float s = 0.f;
#pragma unroll
  for (int i = 0; i < 16; ++i)
    s += W[(long)n * DIMD + lane + i * 64] * bvec[lane + i * 64];
#pragma unroll
  for (int o = 32; o > 0; o >>= 1) s += __shfl_xor(s, o, 64);
  if (lane == 0) outp[n] = s + badd[n];
}

// C = A[M,1024] @ W[1024,1024]^T (+bias), XOR-swizzled LDS (0 bank conflicts).
// Grid (N-blocks, M-blocks[, z]).
// MODE 0: fused interior. blockIdx.x spans 3*1024/TN. seg0: bf16 = acc+b0.
//         seg1/2: bf16 = tanh(acc+b)*aux[col]  (combined-weight phase outputs)
// MODE 1: weight-combine pair via z (A0/W0->O0, A1/W1->O1), bf16 = acc, no bias.
// MODE 2: final. f32 = acc + bias + resid[row*1024+col].
template <int MODE>
__global__ __launch_bounds__(256) void gemm_bt_kernel(
    const unsigned short* __restrict__ A0, const unsigned short* __restrict__ A1,
    const unsigned short* __restrict__ W0, const unsigned short* __restrict__ W1,
    const unsigned short* __restrict__ W2,
    const float* __restrict__ b0, const float* __restrict__ b1,
    const float* __restrict__ b2,
    const float* __restrict__ aux,
    unsigned short* __restrict__ O0, unsigned short* __restrict__ O1,
    unsigned short* __restrict__ O2,
    float* __restrict__ Of, const float* __restrict__ resid)
{
  __shared__ unsigned short lsA[TM * BK];
  __shared__ unsigned short lsB[TN * BK];

  const int tid  = threadIdx.x;
  const int lane = tid & 63;
  const int wid  = tid >> 6;
  const long bm  = (long)blockIdx.y * TM;
  const long bng = (long)blockIdx.x * TN;

  const unsigned short* A = A0;
  const unsigned short* W = W0;
  const float* bias = b0;
  unsigned short* Ob = O0;
  long bn = bng;
  int seg = 0;
  if (MODE == 0) {
    seg = (int)(bng >> 10);
    bn = bng & 1023;
    W    = seg == 0 ? W0 : (seg == 1 ? W1 : W2);
    bias = seg == 0 ? b0 : (seg == 1 ? b1 : b2);
    Ob   = seg == 0 ? O0 : (seg == 1 ? O1 : O2);
  } else if (MODE == 1) {
    if (blockIdx.z) { A = A1; W = W1; Ob = O1; }
  }

  const int wm = (wid & 1) * 64;
  const int wn = (wid >> 1) * 64;

  floatx4 acc[4][4];
#pragma unroll
  for (int i = 0; i < 4; ++i)
#pragma unroll
    for (int j = 0; j < 4; ++j)
      acc[i][j] = (floatx4)(0.0f);

  const int srow  = lane >> 3;
  const int pcol  = (lane & 7) * 8;
  const int lcolL = (((lane & 7) ^ (srow & 7)) * 8);
  const int frm   = lane & 15;
  const int cfrk  = lane >> 4;

  for (int kk = 0; kk < DIMD; kk += BK) {
    __syncthreads();
#pragma unroll
    for (int j = 0; j < 4; ++j) {
      const int inst = wid * 4 + j;
      const int r = inst * 8 + srow;
      async16(A + (bm + r) * (long)DIMD + kk + lcolL, &lsA[r * BK + pcol]);
      async16(W + (bn + r) * (long)DIMD + kk + lcolL, &lsB[r * BK + pcol]);
    }
    __syncthreads();
#pragma unroll
    for (int ks = 0; ks < BK; ks += 32) {
      const int cb  = (ks >> 3) + cfrk;
      const int swz = ((cb ^ (frm & 7)) << 3);
      bf16x8 af[4], bfr[4];
#pragma unroll
      for (int i = 0; i < 4; ++i)
        af[i]  = *(const bf16x8*)&lsA[(wm + i * 16 + frm) * BK + swz];
#pragma unroll
      for (int i = 0; i < 4; ++i)
        bfr[i] = *(const bf16x8*)&lsB[(wn + i * 16 + frm) * BK + swz];
#pragma unroll
      for (int i = 0; i < 4; ++i)
#pragma unroll
        for (int j = 0; j < 4; ++j)
          acc[i][j] = __builtin_amdgcn_mfma_f32_16x16x32_bf16(af[i], bfr[j], acc[i][j], 0, 0, 0);
    }
  }

  const int cn = lane & 15;
  const int rq = (lane >> 4) * 4;
#pragma unroll
  for (int j = 0; j < 4; ++j) {
    const long col = bn + wn + j * 16 + cn;
    const float bv = (MODE == 1) ? 0.0f : bias[col];
    const float pv = (MODE == 0) ? aux[col] : 0.0f;
#pragma unroll
    for (int i = 0; i < 4; ++i) {
#pragma unroll
      for (int r = 0; r < 4; ++r) {
        const long row = bm + wm + i * 16 + rq + r;
        const float v = acc[i][j][r] + bv;
        if (MODE == 0) {
          Ob[row * (long)DIMD + col] = (seg == 0) ? f2bf(v) : f2bf(tanhf(v) * pv);
        } else if (MODE == 1) {
          Ob[row * (long)DIMD + col] = f2bf(v);
        } else {
          Of[row * (long)DIMD + col] = v + resid[row * (long)DIMD + col];
        }
      }
    }
  }
}

// One block per chunk, 256 threads x 4 dims. Two halves of 32 t-steps:
// phase 1 (barrier-free): per-thread scan, retrieved -> LDS (bf16).
// phase 2: per-row LN via wave shuffle reduce, coalesced 16B stores.
__global__ __launch_bounds__(256) void scan_ln_kernel(
    const unsigned short* __restrict__ V,  const unsigned short* __restrict__ KP,
    const unsigned short* __restrict__ QP,
    const float* __restrict__ lng, const float* __restrict__ lnb,
    unsigned short* __restrict__ out)
{
  __shared__ unsigned short ret_s[32][DIMD];   // 64 KB

  const int tid  = threadIdx.x;
  const int lane = tid & 63;
  const int wid  = tid >> 6;
  const long rowBase = (long)blockIdx.x * CHUNKLEN;
  const int d0 = tid * 4;

  const int c0 = lane * 8;
  const int c1 = 512 + lane * 8;
  float g0[8], be0[8], g1[8], be1[8];
#pragma unroll
  for (int j = 0; j < 8; ++j) {
    g0[j] = lng[c0 + j]; be0[j] = lnb[c0 + j];
    g1[j] = lng[c1 + j]; be1[j] = lnb[c1 + j];
  }

  float mr[4] = {0.f, 0.f, 0.f, 0.f};
  float mi[4] = {0.f, 0.f, 0.f, 0.f};

  for (int h = 0; h < 2; ++h) {
    for (int tl = 0; tl < 32; ++tl) {
      const int t = h * 32 + tl;
      const long off = (rowBase + t) * DIMD + d0;
      const ushort4 v4 = *(const ushort4*)(V + off);
      const ushort4 k4 = *(const ushort4*)(KP + off);
      const ushort4 q4 = *(const ushort4*)(QP + off);
      const unsigned short va[4] = {v4.x, v4.y, v4.z, v4.w};
      const unsigned short ka[4] = {k4.x, k4.y, k4.z, k4.w};
      const unsigned short qa[4] = {q4.x, q4.y, q4.z, q4.w};
      ushort4 o4;
      unsigned short rv[4];
#pragma unroll
      for (int j = 0; j < 4; ++j) {
        const float v  = bf2f(va[j]);
        const float kp = bf2f(ka[j]);
        const float qp = bf2f(qa[j]);
        float skp, ckp, sqp, cqp;
        __sincosf(kp, &skp, &ckp);
        __sincosf(qp, &sqp, &cqp);
        mr[j] += v * ckp;
        mi[j] += v * skp;
        rv[j] = f2bf((mr[j] * cqp + mi[j] * sqp) * 0.03125f);
      }
      o4.x = rv[0]; o4.y = rv[1]; o4.z = rv[2]; o4.w = rv[3];
      *(ushort4*)&ret_s[tl][d0] = o4;
    }
    __syncthreads();

#pragma unroll 1
    for (int rr = 0; rr < 8; ++rr) {
      const int tl = wid * 8 + rr;
      const ushort8v a0 = *(const ushort8v*)&ret_s[tl][c0];
      const ushort8v a1 = *(const ushort8v*)&ret_s[tl][c1];
      float f0[8], f1[8];
      float s = 0.f, s2 = 0.f;
#pragma unroll
      for (int j = 0; j < 8; ++j) {
        f0[j] = bf2f(a0[j]); f1[j] = bf2f(a1[j]);
        s += f0[j] + f1[j];
        s2 += f0[j] * f0[j] + f1[j] * f1[j];
      }
#pragma unroll
      for (int o = 32; o > 0; o >>= 1) {
        s  += __shfl_xor(s,  o, 64);
        s2 += __shfl_xor(s2, o, 64);
      }
      const float mu  = s * (1.0f / DIMD);
      const float var = s2 * (1.0f / DIMD) - mu * mu;
      const float inv = rsqrtf(var + 1e-5f);
      ushort8v o0, o1;
#pragma unroll
      for (int j = 0; j < 8; ++j) {
        o0[j] = f2bf((f0[j] - mu) * inv * g0[j] + be0[j]);
        o1[j] = f2bf((f1[j] - mu) * inv * g1[j] + be1[j]);
      }
      const long gro = (rowBase + h * 32 + tl) * DIMD;
      *(ushort8v*)(out + gro + c0) = o0;
      *(ushort8v*)(out + gro + c1) = o1;
    }
    __syncthreads();
  }
}

extern "C" void kernel_launch(void* const* d_in, const int* in_sizes, int n_in,
                              void* d_out, int out_size, void* d_ws, size_t ws_size,
                              hipStream_t stream)
{
  const float* x   = (const float*)d_in[0];
  const float* Wk  = (const float*)d_in[1];
  const float* bk  = (const float*)d_in[2];
  const float* Wv  = (const float*)d_in[3];
  const float* bv  = (const float*)d_in[4];
  const float* Wq  = (const float*)d_in[5];
  const float* bq  = (const float*)d_in[6];
  const float* Wkp = (const float*)d_in[7];
  const float* bkp = (const float*)d_in[8];
  const float* Wqp = (const float*)d_in[9];
  const float* bqp = (const float*)d_in[10];
  const float* ph  = (const float*)d_in[11];
  const float* lng = (const float*)d_in[12];
  const float* lnb = (const float*)d_in[13];
  const float* Wo  = (const float*)d_in[14];
  const float* bo  = (const float*)d_in[15];
  float* out = (float*)d_out;

  const long NB = (long)NTOK * DIMD;
  const long DD = (long)DIMD * DIMD;
  const size_t required = (size_t)(4 * NB + 8 * DD) * sizeof(unsigned short)
                        + 2048 * sizeof(float);
  if (ws_size < required) return;

  unsigned short* S0   = (unsigned short*)d_ws;  // xb, later Rln
  unsigned short* SV   = S0   + NB;
  unsigned short* SKP  = SV   + NB;
  unsigned short* SQP  = SKP  + NB;
  unsigned short* Wvb  = SQP  + NB;
  unsigned short* Wob  = Wvb  + DD;
  unsigned short* Wkpb = Wob  + DD;
  unsigned short* Wqpb = Wkpb + DD;
  unsigned short* WkT  = Wqpb + DD;
  unsigned short* WqT  = WkT  + DD;
  unsigned short* Wkqb = WqT  + DD;
  unsigned short* Wqqb = Wkqb + DD;
  float* bkq = (float*)(Wqqb + DD);
  float* bqq = bkq + DIMD;

  dim3 blk(256);

  // 1) fp32->bf16: x, Wv, Wo, Wkp, Wqp
  cvt_all_kernel<<<dim3(16384 + 4 * 1024), blk, 0, stream>>>(
      x, Wv, Wo, Wkp, Wqp, S0, Wvb, Wob, Wkpb, Wqpb);
  // 2) WkT = Wk^T (bf16), WqT = Wq^T
  transpose_cvt_kernel<<<dim3(16, 16, 2), blk, 0, stream>>>(Wk, Wq, WkT, WqT);
  // 3) combined biases: bkq = Wkp@bk + bkp ; bqq = Wqp@bq + bqp
  bias_comb_kernel<<<dim3(512), blk, 0, stream>>>(Wkp, bk, bkp, Wqp, bq, bqp, bkq, bqq);
  // 4) combined weights: Wkq = Wkp @ (WkT)^T = Wkp@Wk ; Wqq likewise
  gemm_bt_kernel<1><<<dim3(DIMD / TN, DIMD / TM, 2), blk, 0, stream>>>(
      Wkpb, Wqpb, WkT, WqT, nullptr, nullptr, nullptr, nullptr, nullptr,
      Wkqb, Wqqb, nullptr, nullptr, nullptr);
  // 5) fused interior: V | KP = tanh(x@Wkq^T+bkq)*ph | QP = tanh(x@Wqq^T+bqq)*ph
  gemm_bt_kernel<0><<<dim3(3 * DIMD / TN, NTOK / TM), blk, 0, stream>>>(
      S0, nullptr, Wvb, Wkqb, Wqqb, bv, bkq, bqq, ph, SV, SKP, SQP, nullptr, nullptr);
  // 6) scan + layernorm -> Rln (reuses S0)
  scan_ln_kernel<<<dim3(NTOK / CHUNKLEN), blk, 0, stream>>>(SV, SKP, SQP, lng, lnb, S0);
  // 7) out = Rln@Wo^T + bo + x  (fp32)
  gemm_bt_kernel<2><<<dim3(DIMD / TN, NTOK / TM), blk, 0, stream>>>(
      S0, nullptr, Wob, nullptr, nullptr, bo, nullptr, nullptr, nullptr,
      nullptr, nullptr, nullptr, out, x);
}

// Round 6
// 417.968 us; speedup vs baseline: 1.4464x; 1.0789x over previous
//
#include <hip/hip_runtime.h>
#include <math.h>

#define DIMD 1024
#define CHUNKLEN 64
#define NTOK 16384   // B*S = 4*4096

#define TM 128
#define TN 128
#define BK 64

typedef __bf16 bf16x8 __attribute__((ext_vector_type(8)));
typedef float floatx4 __attribute__((ext_vector_type(4)));
typedef unsigned short ushort8v __attribute__((ext_vector_type(8)));

__device__ __forceinline__ float bf2f(unsigned short u) {
  union { unsigned int i; float f; } v; v.i = ((unsigned int)u) << 16; return v.f;
}
__device__ __forceinline__ unsigned short f2bf(float f) {
  union { float f; unsigned int i; } v; v.f = f;
  unsigned int r = v.i + 0x7FFFu + ((v.i >> 16) & 1u);
  return (unsigned short)(r >> 16);
}

// tanh(v) = 1 - 2/(e^{2v}+1); exp->inf gives 1, exp->0 gives -1 (no NaN).
// ~5 VALU ops (v_exp_f32 + v_rcp_f32) vs ~50 for libm tanhf.
__device__ __forceinline__ float tanh_fast(float v) {
  const float t = __expf(2.0f * v);
  return 1.0f - 2.0f * __builtin_amdgcn_rcpf(t + 1.0f);
}

__device__ __forceinline__ void async16(const unsigned short* g, unsigned short* l) {
  __builtin_amdgcn_global_load_lds(
      (const __attribute__((address_space(1))) unsigned int*)g,
      (__attribute__((address_space(3))) unsigned int*)l, 16, 0, 0);
}

// Convert x (16384 blocks) + 4 weights (1024 blocks each) fp32 -> bf16.
__global__ __launch_bounds__(256) void cvt_all_kernel(
    const float* __restrict__ x,
    const float* __restrict__ w0, const float* __restrict__ w1,
    const float* __restrict__ w2, const float* __restrict__ w3,
    unsigned short* __restrict__ dx,
    unsigned short* __restrict__ d0, unsigned short* __restrict__ d1,
    unsigned short* __restrict__ d2, unsigned short* __restrict__ d3)
{
  const int b = blockIdx.x;
  const float* src; unsigned short* dst; long i;
  if (b < 16384) {
    src = x; dst = dx; i = (long)b * 256 + threadIdx.x;
  } else {
    const int r = b - 16384;
    const int s = r >> 10;
    src = s == 0 ? w0 : s == 1 ? w1 : s == 2 ? w2 : w3;
    dst = s == 0 ? d0 : s == 1 ? d1 : s == 2 ? d2 : d3;
    i = (long)(r & 1023) * 256 + threadIdx.x;
  }
  const float4 v = ((const float4*)src)[i];
  ushort4 o;
  o.x = f2bf(v.x); o.y = f2bf(v.y); o.z = f2bf(v.z); o.w = f2bf(v.w);
  ((ushort4*)dst)[i] = o;
}

// dst[k*1024+e] = bf16(src[e*1024+k]) for two matrices (z selects).
__global__ __launch_bounds__(256) void transpose_cvt_kernel(
    const float* __restrict__ s0, const float* __restrict__ s1,
    unsigned short* __restrict__ q0, unsigned short* __restrict__ q1)
{
  __shared__ unsigned short tile[64][66];
  const float* src = blockIdx.z ? s1 : s0;
  unsigned short* dst = blockIdx.z ? q1 : q0;
  const int e0 = blockIdx.y * 64;
  const int k0 = blockIdx.x * 64;
  const int t  = threadIdx.x;
  const int tr = t >> 4;        // 0..15
  const int tc = t & 15;        // 0..15
#pragma unroll
  for (int p = 0; p < 4; ++p) {
    const int el = p * 16 + tr;
    const float4 v = *(const float4*)&src[(long)(e0 + el) * DIMD + k0 + tc * 4];
    tile[el][tc * 4 + 0] = f2bf(v.x);
    tile[el][tc * 4 + 1] = f2bf(v.y);
    tile[el][tc * 4 + 2] = f2bf(v.z);
    tile[el][tc * 4 + 3] = f2bf(v.w);
  }
  __syncthreads();
#pragma unroll
  for (int p = 0; p < 4; ++p) {
    const int kl = p * 16 + tr;
    ushort4 o;
    o.x = tile[tc * 4 + 0][kl];
    o.y = tile[tc * 4 + 1][kl];
    o.z = tile[tc * 4 + 2][kl];
    o.w = tile[tc * 4 + 3][kl];
    *(ushort4*)&dst[(long)(k0 + kl) * DIMD + e0 + tc * 4] = o;
  }
}

// bkq[n] = sum_e Wkp[n,e]*bk[e] + bkp[n]; same for q-pair. 512 blocks x 4 waves.
__global__ __launch_bounds__(256) void bias_comb_kernel(
    const float* __restrict__ Wkp, const float* __restrict__ bk,
    const float* __restrict__ bkp,
    const float* __restrict__ Wqp, const float* __restrict__ bq,
    const float* __restrict__ bqp,
    float* __restrict__ bkq, float* __restrict__ bqq)
{
  const int b = blockIdx.x;
  const int which = b >> 8;
  const int lane = threadIdx.x & 63;
  const int wid  = threadIdx.x >> 6;
  const int n = (b & 255) * 4 + wid;
  const float* W    = which ? Wqp : Wkp;
  const float* bvec = which ? bq  : bk;
  const float* badd = which ? bqp : bkp;
  float*       outp = which ? bqq : bkq;
  float s = 0.f;
#pragma unroll
  for (int i = 0; i < 16; ++i)
    s += W[(long)n * DIMD + lane + i * 64] * bvec[lane + i * 64];
#pragma unroll
  for (int o = 32; o > 0; o >>= 1) s += __shfl_xor(s, o, 64);
  if (lane == 0) outp[n] = s + badd[n];
}

// C = A[M,1024] @ W[1024,1024]^T (+bias), XOR-swizzled LDS (0 bank conflicts).
// Grid (N-blocks, M-blocks[, z]).
// MODE 0: fused interior. blockIdx.x spans 3*1024/TN. seg0: bf16 = acc+b0.
//         seg1/2: bf16 = tanh_fast(acc+b)*aux[col]  (combined-weight phases)
// MODE 1: weight-combine pair via z (A0/W0->O0, A1/W1->O1), bf16 = acc, no bias.
// MODE 2: final. f32 = acc + bias + resid[row*1024+col].
template <int MODE>
__global__ __launch_bounds__(256) void gemm_bt_kernel(
    const unsigned short* __restrict__ A0, const unsigned short* __restrict__ A1,
    const unsigned short* __restrict__ W0, const unsigned short* __restrict__ W1,
    const unsigned short* __restrict__ W2,
    const float* __restrict__ b0, const float* __restrict__ b1,
    const float* __restrict__ b2,
    const float* __restrict__ aux,
    unsigned short* __restrict__ O0, unsigned short* __restrict__ O1,
    unsigned short* __restrict__ O2,
    float* __restrict__ Of, const float* __restrict__ resid)
{
  __shared__ unsigned short lsA[TM * BK];
  __shared__ unsigned short lsB[TN * BK];

  const int tid  = threadIdx.x;
  const int lane = tid & 63;
  const int wid  = tid >> 6;
  const long bm  = (long)blockIdx.y * TM;
  const long bng = (long)blockIdx.x * TN;

  const unsigned short* A = A0;
  const unsigned short* W = W0;
  const float* bias = b0;
  unsigned short* Ob = O0;
  long bn = bng;
  int seg = 0;
  if (MODE == 0) {
    seg = (int)(bng >> 10);
    bn = bng & 1023;
    W    = seg == 0 ? W0 : (seg == 1 ? W1 : W2);
    bias = seg == 0 ? b0 : (seg == 1 ? b1 : b2);
    Ob   = seg == 0 ? O0 : (seg == 1 ? O1 : O2);
  } else if (MODE == 1) {
    if (blockIdx.z) { A = A1; W = W1; Ob = O1; }
  }

  const int wm = (wid & 1) * 64;
  const int wn = (wid >> 1) * 64;

  floatx4 acc[4][4];
#pragma unroll
  for (int i = 0; i < 4; ++i)
#pragma unroll
    for (int j = 0; j < 4; ++j)
      acc[i][j] = (floatx4)(0.0f);

  const int srow  = lane >> 3;
  const int pcol  = (lane & 7) * 8;
  const int lcolL = (((lane & 7) ^ (srow & 7)) * 8);
  const int frm   = lane & 15;
  const int cfrk  = lane >> 4;

  for (int kk = 0; kk < DIMD; kk += BK) {
    __syncthreads();
#pragma unroll
    for (int j = 0; j < 4; ++j) {
      const int inst = wid * 4 + j;
      const int r = inst * 8 + srow;
      async16(A + (bm + r) * (long)DIMD + kk + lcolL, &lsA[r * BK + pcol]);
      async16(W + (bn + r) * (long)DIMD + kk + lcolL, &lsB[r * BK + pcol]);
    }
    __syncthreads();
#pragma unroll
    for (int ks = 0; ks < BK; ks += 32) {
      const int cb  = (ks >> 3) + cfrk;
      const int swz = ((cb ^ (frm & 7)) << 3);
      bf16x8 af[4], bfr[4];
#pragma unroll
      for (int i = 0; i < 4; ++i)
        af[i]  = *(const bf16x8*)&lsA[(wm + i * 16 + frm) * BK + swz];
#pragma unroll
      for (int i = 0; i < 4; ++i)
        bfr[i] = *(const bf16x8*)&lsB[(wn + i * 16 + frm) * BK + swz];
#pragma unroll
      for (int i = 0; i < 4; ++i)
#pragma unroll
        for (int j = 0; j < 4; ++j)
          acc[i][j] = __builtin_amdgcn_mfma_f32_16x16x32_bf16(af[i], bfr[j], acc[i][j], 0, 0, 0);
    }
  }

  const int cn = lane & 15;
  const int rq = (lane >> 4) * 4;
#pragma unroll
  for (int j = 0; j < 4; ++j) {
    const long col = bn + wn + j * 16 + cn;
    const float bv = (MODE == 1) ? 0.0f : bias[col];
    const float pv = (MODE == 0) ? aux[col] : 0.0f;
#pragma unroll
    for (int i = 0; i < 4; ++i) {
#pragma unroll
      for (int r = 0; r < 4; ++r) {
        const long row = bm + wm + i * 16 + rq + r;
        const float v = acc[i][j][r] + bv;
        if (MODE == 0) {
          Ob[row * (long)DIMD + col] = (seg == 0) ? f2bf(v)
                                                  : f2bf(tanh_fast(v) * pv);
        } else if (MODE == 1) {
          Ob[row * (long)DIMD + col] = f2bf(v);
        } else {
          Of[row * (long)DIMD + col] = v + resid[row * (long)DIMD + col];
        }
      }
    }
  }
}

// One block per chunk, 512 threads x 2 dims (8 waves/block -> 2 waves/SIMD).
// Two halves of 32 t-steps: phase 1 (barrier-free) per-thread scan ->
// retrieved bf16 in LDS; phase 2 per-row LN via wave shuffle reduce.
__global__ __launch_bounds__(512) void scan_ln_kernel(
    const unsigned short* __restrict__ V,  const unsigned short* __restrict__ KP,
    const unsigned short* __restrict__ QP,
    const float* __restrict__ lng, const float* __restrict__ lnb,
    unsigned short* __restrict__ out)
{
  __shared__ unsigned short ret_s[32][DIMD];   // 64 KB

  const int tid  = threadIdx.x;
  const int lane = tid & 63;
  const int wid  = tid >> 6;          // 0..7
  const long rowBase = (long)blockIdx.x * CHUNKLEN;
  const int d0 = tid * 2;

  const int c0 = lane * 8;
  const int c1 = 512 + lane * 8;
  float g0[8], be0[8], g1[8], be1[8];
#pragma unroll
  for (int j = 0; j < 8; ++j) {
    g0[j] = lng[c0 + j]; be0[j] = lnb[c0 + j];
    g1[j] = lng[c1 + j]; be1[j] = lnb[c1 + j];
  }

  float mr[2] = {0.f, 0.f};
  float mi[2] = {0.f, 0.f};

  for (int h = 0; h < 2; ++h) {
    // ---- phase 1: scan 32 steps, no barriers ----
    for (int tl = 0; tl < 32; ++tl) {
      const int t = h * 32 + tl;
      const long off = (rowBase + t) * DIMD + d0;
      const ushort2 v2 = *(const ushort2*)(V + off);
      const ushort2 k2 = *(const ushort2*)(KP + off);
      const ushort2 q2 = *(const ushort2*)(QP + off);
      const unsigned short va[2] = {v2.x, v2.y};
      const unsigned short ka[2] = {k2.x, k2.y};
      const unsigned short qa[2] = {q2.x, q2.y};
      unsigned short rv[2];
#pragma unroll
      for (int j = 0; j < 2; ++j) {
        const float v  = bf2f(va[j]);
        const float kp = bf2f(ka[j]);
        const float qp = bf2f(qa[j]);
        float skp, ckp, sqp, cqp;
        __sincosf(kp, &skp, &ckp);
        __sincosf(qp, &sqp, &cqp);
        mr[j] += v * ckp;
        mi[j] += v * skp;
        rv[j] = f2bf((mr[j] * cqp + mi[j] * sqp) * 0.03125f);
      }
      ushort2 o2; o2.x = rv[0]; o2.y = rv[1];
      *(ushort2*)&ret_s[tl][d0] = o2;
    }
    __syncthreads();

    // ---- phase 2: 4 rows per wave, shuffle-reduce LN ----
#pragma unroll 1
    for (int rr = 0; rr < 4; ++rr) {
      const int tl = wid * 4 + rr;
      const ushort8v a0 = *(const ushort8v*)&ret_s[tl][c0];
      const ushort8v a1 = *(const ushort8v*)&ret_s[tl][c1];
      float f0[8], f1[8];
      float s = 0.f, s2 = 0.f;
#pragma unroll
      for (int j = 0; j < 8; ++j) {
        f0[j] = bf2f(a0[j]); f1[j] = bf2f(a1[j]);
        s += f0[j] + f1[j];
        s2 += f0[j] * f0[j] + f1[j] * f1[j];
      }
#pragma unroll
      for (int o = 32; o > 0; o >>= 1) {
        s  += __shfl_xor(s,  o, 64);
        s2 += __shfl_xor(s2, o, 64);
      }
      const float mu  = s * (1.0f / DIMD);
      const float var = s2 * (1.0f / DIMD) - mu * mu;
      const float inv = rsqrtf(var + 1e-5f);
      ushort8v o0, o1;
#pragma unroll
      for (int j = 0; j < 8; ++j) {
        o0[j] = f2bf((f0[j] - mu) * inv * g0[j] + be0[j]);
        o1[j] = f2bf((f1[j] - mu) * inv * g1[j] + be1[j]);
      }
      const long gro = (rowBase + h * 32 + tl) * DIMD;
      *(ushort8v*)(out + gro + c0) = o0;
      *(ushort8v*)(out + gro + c1) = o1;
    }
    __syncthreads();
  }
}

extern "C" void kernel_launch(void* const* d_in, const int* in_sizes, int n_in,
                              void* d_out, int out_size, void* d_ws, size_t ws_size,
                              hipStream_t stream)
{
  const float* x   = (const float*)d_in[0];
  const float* Wk  = (const float*)d_in[1];
  const float* bk  = (const float*)d_in[2];
  const float* Wv  = (const float*)d_in[3];
  const float* bv  = (const float*)d_in[4];
  const float* Wq  = (const float*)d_in[5];
  const float* bq  = (const float*)d_in[6];
  const float* Wkp = (const float*)d_in[7];
  const float* bkp = (const float*)d_in[8];
  const float* Wqp = (const float*)d_in[9];
  const float* bqp = (const float*)d_in[10];
  const float* ph  = (const float*)d_in[11];
  const float* lng = (const float*)d_in[12];
  const float* lnb = (const float*)d_in[13];
  const float* Wo  = (const float*)d_in[14];
  const float* bo  = (const float*)d_in[15];
  float* out = (float*)d_out;

  const long NB = (long)NTOK * DIMD;
  const long DD = (long)DIMD * DIMD;
  const size_t required = (size_t)(4 * NB + 8 * DD) * sizeof(unsigned short)
                        + 2048 * sizeof(float);
  if (ws_size < required) return;

  unsigned short* S0   = (unsigned short*)d_ws;  // xb, later Rln
  unsigned short* SV   = S0   + NB;
  unsigned short* SKP  = SV   + NB;
  unsigned short* SQP  = SKP  + NB;
  unsigned short* Wvb  = SQP  + NB;
  unsigned short* Wob  = Wvb  + DD;
  unsigned short* Wkpb = Wob  + DD;
  unsigned short* Wqpb = Wkpb + DD;
  unsigned short* WkT  = Wqpb + DD;
  unsigned short* WqT  = WkT  + DD;
  unsigned short* Wkqb = WqT  + DD;
  unsigned short* Wqqb = Wkqb + DD;
  float* bkq = (float*)(Wqqb + DD);
  float* bqq = bkq + DIMD;

  dim3 blk(256);

  // 1) fp32->bf16: x, Wv, Wo, Wkp, Wqp
  cvt_all_kernel<<<dim3(16384 + 4 * 1024), blk, 0, stream>>>(
      x, Wv, Wo, Wkp, Wqp, S0, Wvb, Wob, Wkpb, Wqpb);
  // 2) WkT = Wk^T (bf16), WqT = Wq^T
  transpose_cvt_kernel<<<dim3(16, 16, 2), blk, 0, stream>>>(Wk, Wq, WkT, WqT);
  // 3) combined biases: bkq = Wkp@bk + bkp ; bqq = Wqp@bq + bqp
  bias_comb_kernel<<<dim3(512), blk, 0, stream>>>(Wkp, bk, bkp, Wqp, bq, bqp, bkq, bqq);
  // 4) combined weights: Wkq = Wkp @ (WkT)^T = Wkp@Wk ; Wqq likewise
  gemm_bt_kernel<1><<<dim3(DIMD / TN, DIMD / TM, 2), blk, 0, stream>>>(
      Wkpb, Wqpb, WkT, WqT, nullptr, nullptr, nullptr, nullptr, nullptr,
      Wkqb, Wqqb, nullptr, nullptr, nullptr);
  // 5) fused interior: V | KP = tanh(x@Wkq^T+bkq)*ph | QP = tanh(x@Wqq^T+bqq)*ph
  gemm_bt_kernel<0><<<dim3(3 * DIMD / TN, NTOK / TM), blk, 0, stream>>>(
      S0, nullptr, Wvb, Wkqb, Wqqb, bv, bkq, bqq, ph, SV, SKP, SQP, nullptr, nullptr);
  // 6) scan + layernorm -> Rln (reuses S0)
  scan_ln_kernel<<<dim3(NTOK / CHUNKLEN), dim3(512), 0, stream>>>(
      SV, SKP, SQP, lng, lnb, S0);
  // 7) out = Rln@Wo^T + bo + x  (fp32)
  gemm_bt_kernel<2><<<dim3(DIMD / TN, NTOK / TM), blk, 0, stream>>>(
      S0, nullptr, Wob, nullptr, nullptr, bo, nullptr, nullptr, nullptr,
      nullptr, nullptr, nullptr, out, x);
}